// Round 5
// baseline (858.368 us; speedup 1.0000x reference)
//
#include <hip/hip_runtime.h>
#include <hip/hip_bf16.h>

#define VOCAB 29
#define VEC   512
#define HID   1024
#define SEN   64
#define BATCH 2048

typedef __bf16 bf16_t;
typedef bf16_t bf16x8 __attribute__((ext_vector_type(8)));
typedef float  floatx4 __attribute__((ext_vector_type(4)));

// ---------------- prep: W_hh fp32 -> bf16 ----------------
__global__ void cvt_whh(const float* __restrict__ w, bf16_t* __restrict__ o, int n) {
    int i = blockIdx.x * blockDim.x + threadIdx.x;
    if (i < n) o[i] = (bf16_t)w[i];
}

// ---------------- prep: W_cls fp32 [65][1024] -> bf16 padded [80][1024] ----------------
__global__ void cvt_wcls(const float* __restrict__ w, bf16_t* __restrict__ o) {
    int i = blockIdx.x * blockDim.x + threadIdx.x;
    if (i >= 80 * HID) return;
    o[i] = (i < 65 * HID) ? (bf16_t)w[i] : (bf16_t)0.0f;
}

// ---------------- prep: proj[v][h] = dot(emb[v], W_ih[h]) (fp32) ----------------
__global__ void proj_kernel(const float* __restrict__ emb, const float* __restrict__ wih,
                            float* __restrict__ proj) {
    int idx = blockIdx.x * blockDim.x + threadIdx.x;
    if (idx >= VOCAB * HID) return;
    int v = idx / HID, h = idx % HID;
    const float* e = emb + v * VEC;
    const float* w = wih + h * VEC;
    float s = 0.f;
    for (int k = 0; k < VEC; k += 4) {
        float4 ev = *(const float4*)(e + k);
        float4 wv = *(const float4*)(w + k);
        s += ev.x * wv.x + ev.y * wv.y + ev.z * wv.z + ev.w * wv.w;
    }
    proj[idx] = s;
}

// exact identity tanh(x) = 1 - 2/(exp(2x)+1); fp32 rounding error << bf16 ulp
__device__ __forceinline__ float fast_tanh(float x) {
    float e = __expf(2.0f * x);
    return 1.0f - 2.0f / (e + 1.0f);
}

// async global->LDS 16B copy. LDS dest: wave-uniform base + lane*16 (HW rule).
__device__ __forceinline__ void load16_to_lds(const bf16_t* g, bf16_t* l) {
    auto gp = reinterpret_cast<const __attribute__((address_space(1))) unsigned int*>(
        reinterpret_cast<uintptr_t>(g));
    auto lp = reinterpret_cast<__attribute__((address_space(3))) unsigned int*>(
        static_cast<unsigned int>(reinterpret_cast<uintptr_t>(l)));
    __builtin_amdgcn_global_load_lds(gp, lp, 16, 0, 0);
}

__device__ __forceinline__ int flag_ld(const int* p) {
    return __hip_atomic_load(p, __ATOMIC_RELAXED, __HIP_MEMORY_SCOPE_AGENT);
}

// ============================================================================
// v6: PERSISTENT RNN + FINE-GRAINED PRODUCER FLAGS (compute-as-ready).
//   Block (bx,by) consumes K-group g (cols 64g..64g+63) produced by peer
//   (bx,g). Groups processed in fixed order by, by+1, .. by+15 (mod 16):
//   - self group (g=by) needs NO wait (own stores drained -> L2).
//   - each peer flag load ISSUED before current group's compute, CHECKED
//     after (~400cyc MFMA/ds hides L2 RTT). Spin only if truly late.
//   - deterministic accumulation order per block; WAR-safe: stores for t+1
//     happen only after observing all 15 peers >= t (they finished reading
//     the buffer being overwritten). Lead < 2 steps = 2 h-buffers.
//   Replaces v5's serialized {skew + 2xRTT + drain} panel barrier.
//   Flags monotonic (producer stores t+1 after step t); no reset, no ABA.
// ============================================================================
#define BM 128
#define BN 64
#define PANEL_BLKS 16
#define SB() __builtin_amdgcn_sched_barrier(0)

// load A fragments for K-group G (chunks 2G, 2G+1) into buffer B
#define LOAD_G(B, G) {                                               \
    const int c0_ = 2 * (G);                                         \
    afb[B][0] = *(const bf16x8*)(hA + c0_ * 32);                     \
    afb[B][1] = *(const bf16x8*)(hA + 16 * HID + c0_ * 32);          \
    afb[B][2] = *(const bf16x8*)(hA + (c0_ + 1) * 32);               \
    afb[B][3] = *(const bf16x8*)(hA + 16 * HID + (c0_ + 1) * 32); }

// compute K-group G from buffer B: 2 chunks x 8 MFMA, 8 ds_read_b128
#define COMP_G(B, G)                                                 \
    _Pragma("unroll")                                                \
    for (int j = 0; j < 2; j++) {                                    \
        const int c_ = 2 * (G) + j;                                  \
        const int p_ = ((4 * c_ + q) ^ l7) * 8;                      \
        bf16x8 b0 = *(const bf16x8*)&Bsh[l16][p_];                   \
        bf16x8 b1 = *(const bf16x8*)&Bsh[16 + l16][p_];              \
        bf16x8 b2 = *(const bf16x8*)&Bsh[32 + l16][p_];              \
        bf16x8 b3 = *(const bf16x8*)&Bsh[48 + l16][p_];              \
        bf16x8 a0 = afb[B][2 * j], a1 = afb[B][2 * j + 1];           \
        acc[0][0] = __builtin_amdgcn_mfma_f32_16x16x32_bf16(a0, b0, acc[0][0], 0, 0, 0); \
        acc[0][1] = __builtin_amdgcn_mfma_f32_16x16x32_bf16(a0, b1, acc[0][1], 0, 0, 0); \
        acc[0][2] = __builtin_amdgcn_mfma_f32_16x16x32_bf16(a0, b2, acc[0][2], 0, 0, 0); \
        acc[0][3] = __builtin_amdgcn_mfma_f32_16x16x32_bf16(a0, b3, acc[0][3], 0, 0, 0); \
        acc[1][0] = __builtin_amdgcn_mfma_f32_16x16x32_bf16(a1, b0, acc[1][0], 0, 0, 0); \
        acc[1][1] = __builtin_amdgcn_mfma_f32_16x16x32_bf16(a1, b1, acc[1][1], 0, 0, 0); \
        acc[1][2] = __builtin_amdgcn_mfma_f32_16x16x32_bf16(a1, b2, acc[1][2], 0, 0, 0); \
        acc[1][3] = __builtin_amdgcn_mfma_f32_16x16x32_bf16(a1, b3, acc[1][3], 0, 0, 0); \
    }

__global__ __launch_bounds__(256, 1)
void rnn_persist(const bf16_t* __restrict__ whh, const float* __restrict__ proj,
                 const int* __restrict__ x, bf16_t* hbuf, int* scnt)
{
    __shared__ __align__(16) bf16_t Bsh[BN][HID];   // exactly 128 KB -> 1 block/CU
    __shared__ int uni_sh;

    const int tid  = threadIdx.x;
    const int bx   = blockIdx.x, by = blockIdx.y;
    const int m0   = bx * BM;
    const int n0   = by * BN;
    const int wave = tid >> 6;
    const int lane = tid & 63;
    const int wm   = wave * 32;        // 4 waves split m: wave tile 32 x 64
    const int q    = lane >> 4;
    const int l16  = lane & 15;
    const int l7   = l16 & 7;

    int* cnt   = scnt + bx * 64;            // safe-path counter (256B stride)
    int* xmask = scnt + (16 + bx) * 64;     // per-panel XCD mask
    int* fl    = scnt + (32 + bx) * 64;     // 16 producer flags per panel (one 64B line)

    // ---- stage W_hh slice ONCE (async DMA; drained by first __syncthreads).
#pragma unroll
    for (int half = 0; half < 2; half++)
#pragma unroll
        for (int it = 0; it < 16; it++) {
            const int r = it * 4 + wave;
            load16_to_lds(whh + (n0 + r) * HID + half * 512 + (lane ^ (r & 7)) * 8,
                          &Bsh[r][half * 512 + lane * 8]);
        }

    // rows this lane owns (C/D row = q*4+reg, col = l16)
    int rowl[8];
#pragma unroll
    for (int mi = 0; mi < 2; mi++)
#pragma unroll
        for (int r = 0; r < 4; r++) rowl[mi * 4 + r] = m0 + wm + mi * 16 + q * 4 + r;

    // ---- t = 0: h = tanh(proj[x[:,0]]) (h_prev = 0)
    {
        float pv0[8][4];
#pragma unroll
        for (int i = 0; i < 8; i++) {
            const int tok = x[rowl[i] * SEN + 0];
            const float* pr = proj + tok * HID + n0;
#pragma unroll
            for (int ni = 0; ni < 4; ni++) pv0[i][ni] = pr[ni * 16 + l16];
        }
#pragma unroll
        for (int i = 0; i < 8; i++)
#pragma unroll
            for (int ni = 0; ni < 4; ni++)
                hbuf[rowl[i] * HID + n0 + ni * 16 + l16] = (bf16_t)fast_tanh(pv0[i][ni]);
    }

    // tokens for t=1 (prefetched)
    int tk[8];
#pragma unroll
    for (int i = 0; i < 8; i++) tk[i] = x[rowl[i] * SEN + 1];

    // ---- first sync: ALWAYS full release/acquire; publishes XCD mask + flag(step0)
    __syncthreads();   // drains t0 stores AND the B-DMA
    if (tid == 0) {
        __hip_atomic_store(&fl[by], 1, __ATOMIC_RELAXED, __HIP_MEMORY_SCOPE_AGENT);
        const int my_xcd = (int)__builtin_amdgcn_s_getreg((3 << 11) | 20);  // HW_REG_XCC_ID
        __hip_atomic_fetch_or(xmask, 1 << my_xcd, __ATOMIC_RELAXED, __HIP_MEMORY_SCOPE_AGENT);
        __hip_atomic_fetch_add(cnt, 1, __ATOMIC_RELEASE, __HIP_MEMORY_SCOPE_AGENT);
        while (__hip_atomic_load(cnt, __ATOMIC_ACQUIRE, __HIP_MEMORY_SCOPE_AGENT) < PANEL_BLKS)
            __builtin_amdgcn_s_sleep(1);
        const int m = __hip_atomic_load(xmask, __ATOMIC_RELAXED, __HIP_MEMORY_SCOPE_AGENT);
        uni_sh = ((m & (m - 1)) == 0);   // one XCD bit -> same-L2 fast path legal
    }
    __syncthreads();
    asm volatile("buffer_inv" ::: "memory");
    const int fast = uni_sh;

#pragma unroll 1
    for (int t = 1; t < SEN; t++) {
        const bf16_t* h_in  = hbuf + (size_t)((t + 1) & 1) * (BATCH * HID);
        bf16_t*       h_out = hbuf + (size_t)(t & 1) * (BATCH * HID);

        floatx4 acc[2][4];
#pragma unroll
        for (int i = 0; i < 2; i++)
#pragma unroll
            for (int j = 0; j < 4; j++) acc[i][j] = (floatx4){0.f, 0.f, 0.f, 0.f};

        // A-fragment base: lane (q,l16) holds h_in[row][k*32 + q*8 .. +7]
        const bf16_t* hA = h_in + (m0 + wm + l16) * HID + q * 8;
        bf16x8 afb[2][4];   // [buf][chunk(2) x mi(2)] — light double buffer

        // self group: no wait (own stores drained -> L2 fresh after inv)
        LOAD_G(0, by)
        // group by+1: one exposed flag wait (producer usually already flagged)
        {
            const int g1 = (by + 1) & 15;
            if (fast) { while (flag_ld(&fl[g1]) < t) {} }
            LOAD_G(1, g1)
        }
        // proj rows for THIS step (tk prefetched last step) — after AF per FIFO
        float pv[8][4];
#pragma unroll
        for (int i = 0; i < 8; i++) {
            const float* pr = proj + tk[i] * HID + n0;
#pragma unroll
            for (int ni = 0; ni < 4; ni++) pv[i][ni] = pr[ni * 16 + l16];
        }

#pragma unroll
        for (int i = 0; i < 16; i++) {
            const int g   = (by + i) & 15;
            const int gn2 = (by + i + 2) & 15;
            int fv = t;                          // default: pass
            if (i < 14 && fast) fv = flag_ld(&fl[gn2]);   // issue early, check late
            SB();
            COMP_G(i & 1, g)                     // hides the flag-load RTT
            SB();
            if (i < 14) {
                if (fast) { while (fv < t) fv = flag_ld(&fl[gn2]); }
                LOAD_G(i & 1, gn2)               // refill consumed buffer
            }
            if (i == 13 && t < SEN - 1) {        // tokens for t+1 (after last AF issue)
#pragma unroll
                for (int ii = 0; ii < 8; ii++) tk[ii] = x[rowl[ii] * SEN + t + 1];
            }
        }

        // epilogue: + proj, tanh, store
#pragma unroll
        for (int mi = 0; mi < 2; mi++)
#pragma unroll
            for (int r = 0; r < 4; r++)
#pragma unroll
                for (int ni = 0; ni < 4; ni++) {
                    float v = acc[mi][ni][r] + pv[mi * 4 + r][ni];
                    h_out[rowl[mi * 4 + r] * HID + n0 + ni * 16 + l16] = (bf16_t)fast_tanh(v);
                }

        if (t < SEN - 1) {
            __syncthreads();   // vmcnt(0): this block's h stores are in L2
            if (fast) {
                if (tid == 0)
                    __hip_atomic_store(&fl[by], t + 1,
                                       __ATOMIC_RELAXED, __HIP_MEMORY_SCOPE_AGENT);
                // no wait: consumers pull via flags
            } else {
                if (tid == 0) {
                    __hip_atomic_fetch_add(cnt, 1, __ATOMIC_RELEASE, __HIP_MEMORY_SCOPE_AGENT);
                    while (__hip_atomic_load(cnt, __ATOMIC_ACQUIRE, __HIP_MEMORY_SCOPE_AGENT)
                           < PANEL_BLKS * (t + 1))
                        __builtin_amdgcn_s_sleep(1);
                }
                __syncthreads();
            }
            // invalidate CU L1 so step-t h is re-read from (fresh) XCD L2
            asm volatile("buffer_inv" ::: "memory");
        }
    }
}

#undef LOAD_G
#undef COMP_G

// ---------------- classifier: out = h @ W_cls^T + b_cls via MFMA (proven R2) ----------------
#define CBM 128
#define CLDK 72
__global__ __launch_bounds__(256)
void classifier_mfma(const bf16_t* __restrict__ h, const bf16_t* __restrict__ wcls,
                     const float* __restrict__ bcls, float* __restrict__ out)
{
    __shared__ __align__(16) bf16_t Ash[CBM][CLDK];
    __shared__ __align__(16) bf16_t Bsh[80][CLDK];

    const int tid = threadIdx.x;
    const int m0 = blockIdx.x * CBM;
    const int wave = tid >> 6, lane = tid & 63;
    const int wm = wave * 32;
    const int q = lane >> 4, l16 = lane & 15;

    floatx4 acc[2][5];
#pragma unroll
    for (int i = 0; i < 2; i++)
#pragma unroll
        for (int j = 0; j < 5; j++) acc[i][j] = (floatx4){0.f, 0.f, 0.f, 0.f};

    for (int kk = 0; kk < HID; kk += 64) {
#pragma unroll
        for (int it = 0; it < 4; it++) {
            int idx = tid + it * 256, r = idx >> 3, c = (idx & 7) * 8;
            *(uint4*)&Ash[r][c] = *(const uint4*)&h[(m0 + r) * HID + kk + c];
        }
#pragma unroll
        for (int it = 0; it < 3; it++) {
            int idx = tid + it * 256;
            if (idx < 640) {
                int r = idx >> 3, c = (idx & 7) * 8;
                *(uint4*)&Bsh[r][c] = *(const uint4*)&wcls[r * HID + kk + c];
            }
        }
        __syncthreads();
#pragma unroll
        for (int ks = 0; ks < 64; ks += 32) {
            bf16x8 af[2], bfr[5];
#pragma unroll
            for (int mi = 0; mi < 2; mi++)
                af[mi] = *(const bf16x8*)&Ash[wm + mi * 16 + l16][ks + q * 8];
#pragma unroll
            for (int ni = 0; ni < 5; ni++)
                bfr[ni] = *(const bf16x8*)&Bsh[ni * 16 + l16][ks + q * 8];
#pragma unroll
            for (int mi = 0; mi < 2; mi++)
#pragma unroll
                for (int ni = 0; ni < 5; ni++)
                    acc[mi][ni] = __builtin_amdgcn_mfma_f32_16x16x32_bf16(
                        af[mi], bfr[ni], acc[mi][ni], 0, 0, 0);
        }
        __syncthreads();
    }

#pragma unroll
    for (int mi = 0; mi < 2; mi++) {
#pragma unroll
        for (int r = 0; r < 4; r++) {
            int gm = m0 + wm + mi * 16 + q * 4 + r;
#pragma unroll
            for (int ni = 0; ni < 5; ni++) {
                int gn = ni * 16 + l16;
                if (gn < SEN + 1)
                    out[gm * (SEN + 1) + gn] = acc[mi][ni][r] + bcls[gn];
            }
        }
    }
}

extern "C" void kernel_launch(void* const* d_in, const int* in_sizes, int n_in,
                              void* d_out, int out_size, void* d_ws, size_t ws_size,
                              hipStream_t stream)
{
    const int*   x     = (const int*)  d_in[0];
    const float* emb   = (const float*)d_in[1];
    const float* w_ih  = (const float*)d_in[2];
    const float* w_hh  = (const float*)d_in[3];
    const float* w_cls = (const float*)d_in[4];
    const float* b_cls = (const float*)d_in[5];
    float* out = (float*)d_out;

    char* ws = (char*)d_ws;
    bf16_t* whh_bf  = (bf16_t*)ws;                                  // 2 MB
    float*  proj    = (float*)(ws + (2u << 20));                    // 128 KB
    bf16_t* wcls_bf = (bf16_t*)(ws + (2u << 20) + (128u << 10));    // 160 KB
    bf16_t* h0      = (bf16_t*)(ws + (2u << 20) + (288u << 10));    // 4 MB
    bf16_t* h1      = (bf16_t*)(ws + (6u << 20) + (288u << 10));    // 4 MB
    int*    scnt    = (int*)   (ws + (10u << 20) + (288u << 10));   // sync area

    hipMemsetAsync(scnt, 0, 16384, stream);
    cvt_whh<<<(HID * HID) / 256, 256, 0, stream>>>(w_hh, whh_bf, HID * HID);
    proj_kernel<<<(VOCAB * HID + 255) / 256, 256, 0, stream>>>(emb, w_ih, proj);
    cvt_wcls<<<(80 * HID) / 256, 256, 0, stream>>>(w_cls, wcls_bf);

    dim3 grid(BATCH / BM, HID / BN);   // (16,16) = 256 blocks = 1/CU (128 KB LDS)
    rnn_persist<<<grid, 256, 0, stream>>>(whh_bf, proj, x, h0, scnt);

    classifier_mfma<<<BATCH / CBM, 256, 0, stream>>>(h1, wcls_bf, b_cls, out);
}

// Round 6
// 844.196 us; speedup vs baseline: 1.0168x; 1.0168x over previous
//
#include <hip/hip_runtime.h>
#include <hip/hip_bf16.h>

#define VOCAB 29
#define VEC   512
#define HID   1024
#define SEN   64
#define BATCH 2048

typedef __bf16 bf16_t;
typedef bf16_t bf16x8 __attribute__((ext_vector_type(8)));
typedef float  floatx4 __attribute__((ext_vector_type(4)));

// ---------------- prep: W_hh fp32 -> bf16 ----------------
__global__ void cvt_whh(const float* __restrict__ w, bf16_t* __restrict__ o, int n) {
    int i = blockIdx.x * blockDim.x + threadIdx.x;
    if (i < n) o[i] = (bf16_t)w[i];
}

// ---------------- prep: W_cls fp32 [65][1024] -> bf16 padded [80][1024] ----------------
__global__ void cvt_wcls(const float* __restrict__ w, bf16_t* __restrict__ o) {
    int i = blockIdx.x * blockDim.x + threadIdx.x;
    if (i >= 80 * HID) return;
    o[i] = (i < 65 * HID) ? (bf16_t)w[i] : (bf16_t)0.0f;
}

// ---------------- prep: proj[v][h] = dot(emb[v], W_ih[h]) (fp32) ----------------
__global__ void proj_kernel(const float* __restrict__ emb, const float* __restrict__ wih,
                            float* __restrict__ proj) {
    int idx = blockIdx.x * blockDim.x + threadIdx.x;
    if (idx >= VOCAB * HID) return;
    int v = idx / HID, h = idx % HID;
    const float* e = emb + v * VEC;
    const float* w = wih + h * VEC;
    float s = 0.f;
    for (int k = 0; k < VEC; k += 4) {
        float4 ev = *(const float4*)(e + k);
        float4 wv = *(const float4*)(w + k);
        s += ev.x * wv.x + ev.y * wv.y + ev.z * wv.z + ev.w * wv.w;
    }
    proj[idx] = s;
}

// exact identity tanh(x) = 1 - 2/(exp(2x)+1); fp32 rounding error << bf16 ulp
__device__ __forceinline__ float fast_tanh(float x) {
    float e = __expf(2.0f * x);
    return 1.0f - 2.0f / (e + 1.0f);
}

// async global->LDS 16B copy. LDS dest: wave-uniform base + lane*16 (HW rule).
__device__ __forceinline__ void load16_to_lds(const bf16_t* g, bf16_t* l) {
    auto gp = reinterpret_cast<const __attribute__((address_space(1))) unsigned int*>(
        reinterpret_cast<uintptr_t>(g));
    auto lp = reinterpret_cast<__attribute__((address_space(3))) unsigned int*>(
        static_cast<unsigned int>(reinterpret_cast<uintptr_t>(l)));
    __builtin_amdgcn_global_load_lds(gp, lp, 16, 0, 0);
}

__device__ __forceinline__ int flag_ld(const int* p) {
    return __hip_atomic_load(p, __ATOMIC_RELAXED, __HIP_MEMORY_SCOPE_AGENT);
}

// ============================================================================
// v7: PERSISTENT RNN, producer flags + ONE-SHOT PARALLEL POLL + 4-GROUP RING.
//   v5 (640cyc lookahead, barrier) = 689us; v6 (flags, 240cyc lookahead) =
//   800us -> the regression was prefetch distance < post-inv L2 latency plus
//   16 serial flag polls. v7:
//   - poll ALL 15 peer flags at once (15 lanes, 1 RTT) -> __ballot ready-mask;
//     per-group spin only for genuinely-late producers.
//   - afb[4][4] ring: compute group i, refill group i+4 (320-640cyc cover).
//   - sched_barrier(0) between every flag observation and the peer A-loads
//     (relaxed atomics impose no compile-time order on other loads - v6 had
//     this race latent).
//   Flag semantics (unchanged, proven v6): fl[by]=t+1 after step-t stores
//   drained; consumer at step t loads group g only after fl[g] >= t.
//   WAR-safe across the 2 h-buffers; deterministic accumulation order.
// ============================================================================
#define BM 128
#define BN 64
#define PANEL_BLKS 16
#define SB() __builtin_amdgcn_sched_barrier(0)

// load A fragments for K-group G (chunks 2G, 2G+1) into ring buffer B
#define LOAD_G(B, G) {                                               \
    const int c0_ = 2 * (G);                                         \
    afb[B][0] = *(const bf16x8*)(hA + c0_ * 32);                     \
    afb[B][1] = *(const bf16x8*)(hA + 16 * HID + c0_ * 32);          \
    afb[B][2] = *(const bf16x8*)(hA + (c0_ + 1) * 32);               \
    afb[B][3] = *(const bf16x8*)(hA + 16 * HID + (c0_ + 1) * 32); }

// wait for producer of group (by+J): wave-uniform mask test, spin if late.
// SB() after: forbid hoisting subsequent A-loads above the observation.
#define WAITG(J) {                                                   \
    if (!((ready >> ((J) - 1)) & 1ull)) {                            \
        const int g_ = (by + (J)) & 15;                              \
        while (flag_ld(&fl[g_]) < t) {}                              \
    }                                                                \
    SB(); }

// compute K-group G from ring buffer B: 2 chunks x 8 MFMA, 8 ds_read_b128
#define COMP_G(B, G)                                                 \
    _Pragma("unroll")                                                \
    for (int j = 0; j < 2; j++) {                                    \
        const int c_ = 2 * (G) + j;                                  \
        const int p_ = ((4 * c_ + q) ^ l7) * 8;                      \
        bf16x8 b0 = *(const bf16x8*)&Bsh[l16][p_];                   \
        bf16x8 b1 = *(const bf16x8*)&Bsh[16 + l16][p_];              \
        bf16x8 b2 = *(const bf16x8*)&Bsh[32 + l16][p_];              \
        bf16x8 b3 = *(const bf16x8*)&Bsh[48 + l16][p_];              \
        bf16x8 a0 = afb[B][2 * j], a1 = afb[B][2 * j + 1];           \
        acc[0][0] = __builtin_amdgcn_mfma_f32_16x16x32_bf16(a0, b0, acc[0][0], 0, 0, 0); \
        acc[0][1] = __builtin_amdgcn_mfma_f32_16x16x32_bf16(a0, b1, acc[0][1], 0, 0, 0); \
        acc[0][2] = __builtin_amdgcn_mfma_f32_16x16x32_bf16(a0, b2, acc[0][2], 0, 0, 0); \
        acc[0][3] = __builtin_amdgcn_mfma_f32_16x16x32_bf16(a0, b3, acc[0][3], 0, 0, 0); \
        acc[1][0] = __builtin_amdgcn_mfma_f32_16x16x32_bf16(a1, b0, acc[1][0], 0, 0, 0); \
        acc[1][1] = __builtin_amdgcn_mfma_f32_16x16x32_bf16(a1, b1, acc[1][1], 0, 0, 0); \
        acc[1][2] = __builtin_amdgcn_mfma_f32_16x16x32_bf16(a1, b2, acc[1][2], 0, 0, 0); \
        acc[1][3] = __builtin_amdgcn_mfma_f32_16x16x32_bf16(a1, b3, acc[1][3], 0, 0, 0); \
    }

__global__ __launch_bounds__(256, 1)
void rnn_persist(const bf16_t* __restrict__ whh, const float* __restrict__ proj,
                 const int* __restrict__ x, bf16_t* hbuf, int* scnt)
{
    __shared__ __align__(16) bf16_t Bsh[BN][HID];   // exactly 128 KB -> 1 block/CU
    __shared__ int uni_sh;

    const int tid  = threadIdx.x;
    const int bx   = blockIdx.x, by = blockIdx.y;
    const int m0   = bx * BM;
    const int n0   = by * BN;
    const int wave = tid >> 6;
    const int lane = tid & 63;
    const int wm   = wave * 32;        // 4 waves split m: wave tile 32 x 64
    const int q    = lane >> 4;
    const int l16  = lane & 15;
    const int l7   = l16 & 7;

    int* cnt   = scnt + bx * 64;            // safe-path counter (256B stride)
    int* xmask = scnt + (16 + bx) * 64;     // per-panel XCD mask
    int* fl    = scnt + (32 + bx) * 64;     // 16 producer flags per panel

    // ---- stage W_hh slice ONCE (async DMA; drained by first __syncthreads).
#pragma unroll
    for (int half = 0; half < 2; half++)
#pragma unroll
        for (int it = 0; it < 16; it++) {
            const int r = it * 4 + wave;
            load16_to_lds(whh + (n0 + r) * HID + half * 512 + (lane ^ (r & 7)) * 8,
                          &Bsh[r][half * 512 + lane * 8]);
        }

    // rows this lane owns (C/D row = q*4+reg, col = l16)
    int rowl[8];
#pragma unroll
    for (int mi = 0; mi < 2; mi++)
#pragma unroll
        for (int r = 0; r < 4; r++) rowl[mi * 4 + r] = m0 + wm + mi * 16 + q * 4 + r;

    // ---- t = 0: h = tanh(proj[x[:,0]]) (h_prev = 0)
    {
        float pv0[8][4];
#pragma unroll
        for (int i = 0; i < 8; i++) {
            const int tok = x[rowl[i] * SEN + 0];
            const float* pr = proj + tok * HID + n0;
#pragma unroll
            for (int ni = 0; ni < 4; ni++) pv0[i][ni] = pr[ni * 16 + l16];
        }
#pragma unroll
        for (int i = 0; i < 8; i++)
#pragma unroll
            for (int ni = 0; ni < 4; ni++)
                hbuf[rowl[i] * HID + n0 + ni * 16 + l16] = (bf16_t)fast_tanh(pv0[i][ni]);
    }

    // tokens for t=1 (prefetched)
    int tk[8];
#pragma unroll
    for (int i = 0; i < 8; i++) tk[i] = x[rowl[i] * SEN + 1];

    // ---- first sync: ALWAYS full release/acquire; publishes XCD mask + flag(step0)
    __syncthreads();   // drains t0 stores AND the B-DMA
    if (tid == 0) {
        __hip_atomic_store(&fl[by], 1, __ATOMIC_RELAXED, __HIP_MEMORY_SCOPE_AGENT);
        const int my_xcd = (int)__builtin_amdgcn_s_getreg((3 << 11) | 20);  // HW_REG_XCC_ID
        __hip_atomic_fetch_or(xmask, 1 << my_xcd, __ATOMIC_RELAXED, __HIP_MEMORY_SCOPE_AGENT);
        __hip_atomic_fetch_add(cnt, 1, __ATOMIC_RELEASE, __HIP_MEMORY_SCOPE_AGENT);
        while (__hip_atomic_load(cnt, __ATOMIC_ACQUIRE, __HIP_MEMORY_SCOPE_AGENT) < PANEL_BLKS)
            __builtin_amdgcn_s_sleep(1);
        const int m = __hip_atomic_load(xmask, __ATOMIC_RELAXED, __HIP_MEMORY_SCOPE_AGENT);
        uni_sh = ((m & (m - 1)) == 0);   // one XCD bit -> same-L2 fast path legal
    }
    __syncthreads();
    asm volatile("buffer_inv" ::: "memory");
    const int fast = uni_sh;

#pragma unroll 1
    for (int t = 1; t < SEN; t++) {
        const bf16_t* h_in  = hbuf + (size_t)((t + 1) & 1) * (BATCH * HID);
        bf16_t*       h_out = hbuf + (size_t)(t & 1) * (BATCH * HID);

        floatx4 acc[2][4];
#pragma unroll
        for (int i = 0; i < 2; i++)
#pragma unroll
            for (int j = 0; j < 4; j++) acc[i][j] = (floatx4){0.f, 0.f, 0.f, 0.f};

        // A-fragment base: lane (q,l16) holds h_in[row][k*32 + q*8 .. +7]
        const bf16_t* hA = h_in + (m0 + wm + l16) * HID + q * 8;
        bf16x8 afb[4][4];   // 4-group ring = 64 VGPR; budget 512 (1 wave/SIMD)

        // self group: no wait (own stores drained; own L1 lines fresh)
        LOAD_G(0, by)

        // ---- one-shot parallel poll of all 15 peers (1 L2 RTT, hidden by g0)
        unsigned long long ready;
        if (fast) {
            int f_ = t;   // lanes >=15 report ready
            if (lane < 15) f_ = flag_ld(&fl[(by + 1 + lane) & 15]);
            ready = __ballot(f_ >= t);   // bit i <=> group (by+1+i) ready
        } else {
            ready = ~0ull;               // safe mode: barrier below guarantees order
        }
        SB();   // nothing below may hoist above the poll

        WAITG(1) LOAD_G(1, (by + 1) & 15)
        WAITG(2) LOAD_G(2, (by + 2) & 15)
        WAITG(3) LOAD_G(3, (by + 3) & 15)

        // proj rows for THIS step (tk prefetched last step); used at epilogue
        float pv[8][4];
#pragma unroll
        for (int i = 0; i < 8; i++) {
            const float* pr = proj + tk[i] * HID + n0;
#pragma unroll
            for (int ni = 0; ni < 4; ni++) pv[i][ni] = pr[ni * 16 + l16];
        }
        SB();

        // ---- main ring: compute group i, refill group i+4 ------------------
#pragma unroll
        for (int i = 0; i < 16; i++) {
            const int g = (by + i) & 15;
            COMP_G(i & 3, g)
            SB();
            if (i + 4 < 16) {
                WAITG(i + 4)
                LOAD_G(i & 3, (by + i + 4) & 15)
                SB();
            }
        }

        // tokens for t+1 (consumed early next step; full sync-gap to return)
        if (t < SEN - 1) {
#pragma unroll
            for (int i = 0; i < 8; i++) tk[i] = x[rowl[i] * SEN + t + 1];
        }

        // epilogue: + proj, tanh, store
#pragma unroll
        for (int mi = 0; mi < 2; mi++)
#pragma unroll
            for (int r = 0; r < 4; r++)
#pragma unroll
                for (int ni = 0; ni < 4; ni++) {
                    float v = acc[mi][ni][r] + pv[mi * 4 + r][ni];
                    h_out[rowl[mi * 4 + r] * HID + n0 + ni * 16 + l16] = (bf16_t)fast_tanh(v);
                }

        if (t < SEN - 1) {
            __syncthreads();   // vmcnt(0): this block's h stores are in L2
            if (fast) {
                if (tid == 0)
                    __hip_atomic_store(&fl[by], t + 1,
                                       __ATOMIC_RELAXED, __HIP_MEMORY_SCOPE_AGENT);
                // no wait: consumers pull via flags
            } else {
                if (tid == 0) {
                    __hip_atomic_fetch_add(cnt, 1, __ATOMIC_RELEASE, __HIP_MEMORY_SCOPE_AGENT);
                    while (__hip_atomic_load(cnt, __ATOMIC_ACQUIRE, __HIP_MEMORY_SCOPE_AGENT)
                           < PANEL_BLKS * (t + 1))
                        __builtin_amdgcn_s_sleep(1);
                }
                __syncthreads();
            }
            // invalidate CU L1 so step-t h is re-read from (fresh) XCD L2
            asm volatile("buffer_inv" ::: "memory");
        }
    }
}

#undef LOAD_G
#undef COMP_G
#undef WAITG

// ---------------- classifier: out = h @ W_cls^T + b_cls via MFMA (proven R2) ----------------
#define CBM 128
#define CLDK 72
__global__ __launch_bounds__(256)
void classifier_mfma(const bf16_t* __restrict__ h, const bf16_t* __restrict__ wcls,
                     const float* __restrict__ bcls, float* __restrict__ out)
{
    __shared__ __align__(16) bf16_t Ash[CBM][CLDK];
    __shared__ __align__(16) bf16_t Bsh[80][CLDK];

    const int tid = threadIdx.x;
    const int m0 = blockIdx.x * CBM;
    const int wave = tid >> 6, lane = tid & 63;
    const int wm = wave * 32;
    const int q = lane >> 4, l16 = lane & 15;

    floatx4 acc[2][5];
#pragma unroll
    for (int i = 0; i < 2; i++)
#pragma unroll
        for (int j = 0; j < 5; j++) acc[i][j] = (floatx4){0.f, 0.f, 0.f, 0.f};

    for (int kk = 0; kk < HID; kk += 64) {
#pragma unroll
        for (int it = 0; it < 4; it++) {
            int idx = tid + it * 256, r = idx >> 3, c = (idx & 7) * 8;
            *(uint4*)&Ash[r][c] = *(const uint4*)&h[(m0 + r) * HID + kk + c];
        }
#pragma unroll
        for (int it = 0; it < 3; it++) {
            int idx = tid + it * 256;
            if (idx < 640) {
                int r = idx >> 3, c = (idx & 7) * 8;
                *(uint4*)&Bsh[r][c] = *(const uint4*)&wcls[r * HID + kk + c];
            }
        }
        __syncthreads();
#pragma unroll
        for (int ks = 0; ks < 64; ks += 32) {
            bf16x8 af[2], bfr[5];
#pragma unroll
            for (int mi = 0; mi < 2; mi++)
                af[mi] = *(const bf16x8*)&Ash[wm + mi * 16 + l16][ks + q * 8];
#pragma unroll
            for (int ni = 0; ni < 5; ni++)
                bfr[ni] = *(const bf16x8*)&Bsh[ni * 16 + l16][ks + q * 8];
#pragma unroll
            for (int mi = 0; mi < 2; mi++)
#pragma unroll
                for (int ni = 0; ni < 5; ni++)
                    acc[mi][ni] = __builtin_amdgcn_mfma_f32_16x16x32_bf16(
                        af[mi], bfr[ni], acc[mi][ni], 0, 0, 0);
        }
        __syncthreads();
    }

#pragma unroll
    for (int mi = 0; mi < 2; mi++) {
#pragma unroll
        for (int r = 0; r < 4; r++) {
            int gm = m0 + wm + mi * 16 + q * 4 + r;
#pragma unroll
            for (int ni = 0; ni < 5; ni++) {
                int gn = ni * 16 + l16;
                if (gn < SEN + 1)
                    out[gm * (SEN + 1) + gn] = acc[mi][ni][r] + bcls[gn];
            }
        }
    }
}

extern "C" void kernel_launch(void* const* d_in, const int* in_sizes, int n_in,
                              void* d_out, int out_size, void* d_ws, size_t ws_size,
                              hipStream_t stream)
{
    const int*   x     = (const int*)  d_in[0];
    const float* emb   = (const float*)d_in[1];
    const float* w_ih  = (const float*)d_in[2];
    const float* w_hh  = (const float*)d_in[3];
    const float* w_cls = (const float*)d_in[4];
    const float* b_cls = (const float*)d_in[5];
    float* out = (float*)d_out;

    char* ws = (char*)d_ws;
    bf16_t* whh_bf  = (bf16_t*)ws;                                  // 2 MB
    float*  proj    = (float*)(ws + (2u << 20));                    // 128 KB
    bf16_t* wcls_bf = (bf16_t*)(ws + (2u << 20) + (128u << 10));    // 160 KB
    bf16_t* h0      = (bf16_t*)(ws + (2u << 20) + (288u << 10));    // 4 MB
    bf16_t* h1      = (bf16_t*)(ws + (6u << 20) + (288u << 10));    // 4 MB
    int*    scnt    = (int*)   (ws + (10u << 20) + (288u << 10));   // sync area

    hipMemsetAsync(scnt, 0, 16384, stream);
    cvt_whh<<<(HID * HID) / 256, 256, 0, stream>>>(w_hh, whh_bf, HID * HID);
    proj_kernel<<<(VOCAB * HID + 255) / 256, 256, 0, stream>>>(emb, w_ih, proj);
    cvt_wcls<<<(80 * HID) / 256, 256, 0, stream>>>(w_cls, wcls_bf);

    dim3 grid(BATCH / BM, HID / BN);   // (16,16) = 256 blocks = 1/CU (128 KB LDS)
    rnn_persist<<<grid, 256, 0, stream>>>(whh_bf, proj, x, h0, scnt);

    classifier_mfma<<<BATCH / CBM, 256, 0, stream>>>(h1, wcls_bf, b_cls, out);
}

// Round 7
// 709.823 us; speedup vs baseline: 1.2093x; 1.1893x over previous
//
#include <hip/hip_runtime.h>
#include <hip/hip_bf16.h>

#define VOCAB 29
#define VEC   512
#define HID   1024
#define SEN   64
#define BATCH 2048

typedef __bf16 bf16_t;
typedef bf16_t bf16x8 __attribute__((ext_vector_type(8)));
typedef float  floatx4 __attribute__((ext_vector_type(4)));

// ---------------- prep: W_hh fp32 -> bf16 ----------------
__global__ void cvt_whh(const float* __restrict__ w, bf16_t* __restrict__ o, int n) {
    int i = blockIdx.x * blockDim.x + threadIdx.x;
    if (i < n) o[i] = (bf16_t)w[i];
}

// ---------------- prep: W_cls fp32 [65][1024] -> bf16 padded [80][1024] ----------------
__global__ void cvt_wcls(const float* __restrict__ w, bf16_t* __restrict__ o) {
    int i = blockIdx.x * blockDim.x + threadIdx.x;
    if (i >= 80 * HID) return;
    o[i] = (i < 65 * HID) ? (bf16_t)w[i] : (bf16_t)0.0f;
}

// ---------------- prep: proj[v][h] = dot(emb[v], W_ih[h]) (fp32) ----------------
__global__ void proj_kernel(const float* __restrict__ emb, const float* __restrict__ wih,
                            float* __restrict__ proj) {
    int idx = blockIdx.x * blockDim.x + threadIdx.x;
    if (idx >= VOCAB * HID) return;
    int v = idx / HID, h = idx % HID;
    const float* e = emb + v * VEC;
    const float* w = wih + h * VEC;
    float s = 0.f;
    for (int k = 0; k < VEC; k += 4) {
        float4 ev = *(const float4*)(e + k);
        float4 wv = *(const float4*)(w + k);
        s += ev.x * wv.x + ev.y * wv.y + ev.z * wv.z + ev.w * wv.w;
    }
    proj[idx] = s;
}

// exact identity tanh(x) = 1 - 2/(exp(2x)+1); fp32 rounding error << bf16 ulp
__device__ __forceinline__ float fast_tanh(float x) {
    float e = __expf(2.0f * x);
    return 1.0f - 2.0f / (e + 1.0f);
}

// async global->LDS 16B copy. LDS dest: wave-uniform base + lane*16 (HW rule).
__device__ __forceinline__ void load16_to_lds(const bf16_t* g, bf16_t* l) {
    auto gp = reinterpret_cast<const __attribute__((address_space(1))) unsigned int*>(
        reinterpret_cast<uintptr_t>(g));
    auto lp = reinterpret_cast<__attribute__((address_space(3))) unsigned int*>(
        static_cast<unsigned int>(reinterpret_cast<uintptr_t>(l)));
    __builtin_amdgcn_global_load_lds(gp, lp, 16, 0, 0);
}

// ============================================================================
// v8: PERSISTENT RNN, 8 WAVES / BLOCK -> 2 waves per SIMD (TLP fix).
//   v4-v7 all pinned at ~11us/step with 1 wave/SIMD: per-SIMD 16x16x32 MFMA
//   occupancy is ~19.4cyc (2075TF chip ceiling / 1024 SIMDs), so 256 MFMA =
//   ~4966cyc/step of pure matrix-pipe, and EVERY waitcnt was dead time (no
//   co-resident wave). Scheduling couldn't fix it (v5 689 -> v6/v7 795).
//   v8: 512 thr, 8 waves, wave tile 16x64 (m-split). Same Bsh=128KB, same
//   1 block/CU, same grid (16,16), ZERO change in L2 A-traffic; LDS B-reads
//   double (still < matrix-pipe term). Wave-mate fills stalls (m114).
//   Sync: v5's proven panel barrier (fast relaxed / safe release-acquire) +
//   per-step CU-L1 buffer_inv. K-order ascending (numerics == v5).
// ============================================================================
#define BM 128
#define BN 64
#define PANEL_BLKS 16
#define SB() __builtin_amdgcn_sched_barrier(0)

// load A fragments for K-group G (chunks 2G,2G+1): 1 m-frag x 2 chunks
#define LOAD_G(B, G) {                                               \
    const int c0_ = 2 * (G);                                         \
    afb[B][0] = *(const bf16x8*)(hA + c0_ * 32);                     \
    afb[B][1] = *(const bf16x8*)(hA + (c0_ + 1) * 32); }

// compute K-group G from ring slot B: 2 chunks x {4 ds_read_b128, 4 MFMA}
#define COMP_G(B, G)                                                 \
    _Pragma("unroll")                                                \
    for (int j = 0; j < 2; j++) {                                    \
        const int c_ = 2 * (G) + j;                                  \
        const int p_ = ((4 * c_ + q) ^ l7) * 8;                      \
        bf16x8 b0 = *(const bf16x8*)&Bsh[l16][p_];                   \
        bf16x8 b1 = *(const bf16x8*)&Bsh[16 + l16][p_];              \
        bf16x8 b2 = *(const bf16x8*)&Bsh[32 + l16][p_];              \
        bf16x8 b3 = *(const bf16x8*)&Bsh[48 + l16][p_];              \
        bf16x8 a0 = afb[B][j];                                       \
        acc[0] = __builtin_amdgcn_mfma_f32_16x16x32_bf16(a0, b0, acc[0], 0, 0, 0); \
        acc[1] = __builtin_amdgcn_mfma_f32_16x16x32_bf16(a0, b1, acc[1], 0, 0, 0); \
        acc[2] = __builtin_amdgcn_mfma_f32_16x16x32_bf16(a0, b2, acc[2], 0, 0, 0); \
        acc[3] = __builtin_amdgcn_mfma_f32_16x16x32_bf16(a0, b3, acc[3], 0, 0, 0); \
    }

__global__ __launch_bounds__(512, 2)
void rnn_persist(const bf16_t* __restrict__ whh, const float* __restrict__ proj,
                 const int* __restrict__ x, bf16_t* hbuf, int* scnt)
{
    __shared__ __align__(16) bf16_t Bsh[BN][HID];   // exactly 128 KB -> 1 block/CU
    __shared__ int uni_sh;

    const int tid  = threadIdx.x;
    const int bx   = blockIdx.x, by = blockIdx.y;
    const int m0   = bx * BM;
    const int n0   = by * BN;
    const int wave = tid >> 6;         // 8 waves
    const int lane = tid & 63;
    const int wm   = wave * 16;        // wave tile 16 x 64 (m-split 8 ways)
    const int q    = lane >> 4;
    const int l16  = lane & 15;
    const int l7   = l16 & 7;

    int* cnt   = scnt + bx * 64;            // per-panel counter (256B stride)
    int* xmask = scnt + (16 + bx) * 64;     // per-panel XCD mask

    // ---- stage W_hh slice ONCE: 8 waves x 8 rows per half; dest lane-linear
    //      (DMA rule), source 16B-chunk XOR'd: phys = glob ^ (r&7).
#pragma unroll
    for (int half = 0; half < 2; half++)
#pragma unroll
        for (int it = 0; it < 8; it++) {
            const int r = it * 8 + wave;
            load16_to_lds(whh + (n0 + r) * HID + half * 512 + (lane ^ (r & 7)) * 8,
                          &Bsh[r][half * 512 + lane * 8]);
        }

    // rows this lane owns (C/D row = q*4+reg, col = l16)
    int rowl[4];
#pragma unroll
    for (int r = 0; r < 4; r++) rowl[r] = m0 + wm + q * 4 + r;

    // ---- t = 0: h = tanh(proj[x[:,0]]) (h_prev = 0)
    {
        float pv0[4][4];
#pragma unroll
        for (int i = 0; i < 4; i++) {
            const int tok = x[rowl[i] * SEN + 0];
            const float* pr = proj + tok * HID + n0;
#pragma unroll
            for (int ni = 0; ni < 4; ni++) pv0[i][ni] = pr[ni * 16 + l16];
        }
#pragma unroll
        for (int i = 0; i < 4; i++)
#pragma unroll
            for (int ni = 0; ni < 4; ni++)
                hbuf[rowl[i] * HID + n0 + ni * 16 + l16] = (bf16_t)fast_tanh(pv0[i][ni]);
    }

    // tokens for t=1 (prefetched)
    int tk[4];
#pragma unroll
    for (int i = 0; i < 4; i++) tk[i] = x[rowl[i] * SEN + 1];

    // ---- first sync: ALWAYS full release/acquire; publishes XCD mask
    __syncthreads();   // drains t0 stores AND the B-DMA (vmcnt covers global_load_lds)
    if (tid == 0) {
        const int my_xcd = (int)__builtin_amdgcn_s_getreg((3 << 11) | 20);  // HW_REG_XCC_ID
        __hip_atomic_fetch_or(xmask, 1 << my_xcd, __ATOMIC_RELAXED, __HIP_MEMORY_SCOPE_AGENT);
        __hip_atomic_fetch_add(cnt, 1, __ATOMIC_RELEASE, __HIP_MEMORY_SCOPE_AGENT);
        while (__hip_atomic_load(cnt, __ATOMIC_ACQUIRE, __HIP_MEMORY_SCOPE_AGENT) < PANEL_BLKS)
            __builtin_amdgcn_s_sleep(1);
        const int m = __hip_atomic_load(xmask, __ATOMIC_RELAXED, __HIP_MEMORY_SCOPE_AGENT);
        uni_sh = ((m & (m - 1)) == 0);   // one XCD bit -> same-L2 fast path legal
    }
    __syncthreads();
    asm volatile("buffer_inv" ::: "memory");
    const int fast = uni_sh;

#pragma unroll 1
    for (int t = 1; t < SEN; t++) {
        const bf16_t* h_in  = hbuf + (size_t)((t + 1) & 1) * (BATCH * HID);
        bf16_t*       h_out = hbuf + (size_t)(t & 1) * (BATCH * HID);

        floatx4 acc[4];
#pragma unroll
        for (int j = 0; j < 4; j++) acc[j] = (floatx4){0.f, 0.f, 0.f, 0.f};

        // A-fragment base: lane (q,l16) holds h_in[wm+l16][k*32 + q*8 .. +7]
        const bf16_t* hA = h_in + (m0 + wm + l16) * HID + q * 8;
        bf16x8 afb[4][2];   // 4-group ring, 32 VGPR

        // prologue: prefetch groups 0..3 (8 x 16B loads, ~700cyc ahead of use)
        LOAD_G(0, 0) LOAD_G(1, 1) LOAD_G(2, 2) LOAD_G(3, 3)

        // proj rows for THIS step (tk prefetched last step); used at epilogue
        float pv[4][4];
#pragma unroll
        for (int i = 0; i < 4; i++) {
            const float* pr = proj + tk[i] * HID + n0;
#pragma unroll
            for (int ni = 0; ni < 4; ni++) pv[i][ni] = pr[ni * 16 + l16];
        }
        SB();

        // ---- main ring: compute group i, refill slot with group i+4 --------
#pragma unroll
        for (int i = 0; i < 16; i++) {
            COMP_G(i & 3, i)
            if (i < 12) { LOAD_G(i & 3, i + 4) }
            if (i == 12 && t < SEN - 1) {   // tokens for t+1, off critical path
#pragma unroll
                for (int ii = 0; ii < 4; ii++) tk[ii] = x[rowl[ii] * SEN + t + 1];
            }
            SB();   // loads issued before next group's compute region
        }

        // epilogue: + proj, tanh, store
#pragma unroll
        for (int r = 0; r < 4; r++)
#pragma unroll
            for (int ni = 0; ni < 4; ni++) {
                float v = acc[ni][r] + pv[r][ni];
                h_out[rowl[r] * HID + n0 + ni * 16 + l16] = (bf16_t)fast_tanh(v);
            }

        // ---- panel sync (skip after final step) ---------------------------
        if (t < SEN - 1) {
            __syncthreads();   // vmcnt(0): this block's h stores are in L2
            if (fast) {        // same-L2: relaxed counter, no cache maintenance
                if (tid == 0) {
                    __hip_atomic_fetch_add(cnt, 1, __ATOMIC_RELAXED, __HIP_MEMORY_SCOPE_AGENT);
                    while (__hip_atomic_load(cnt, __ATOMIC_RELAXED, __HIP_MEMORY_SCOPE_AGENT)
                           < PANEL_BLKS * (t + 1))
                        __builtin_amdgcn_s_sleep(1);
                }
            } else {           // cross-XCD fallback: full release/acquire
                if (tid == 0) {
                    __hip_atomic_fetch_add(cnt, 1, __ATOMIC_RELEASE, __HIP_MEMORY_SCOPE_AGENT);
                    while (__hip_atomic_load(cnt, __ATOMIC_ACQUIRE, __HIP_MEMORY_SCOPE_AGENT)
                           < PANEL_BLKS * (t + 1))
                        __builtin_amdgcn_s_sleep(1);
                }
            }
            __syncthreads();
            // invalidate CU L1 so step-t h is re-read from (fresh) XCD L2
            asm volatile("buffer_inv" ::: "memory");
        }
    }
}

#undef LOAD_G
#undef COMP_G

// ---------------- classifier: out = h @ W_cls^T + b_cls via MFMA (proven R2) ----------------
#define CBM 128
#define CLDK 72
__global__ __launch_bounds__(256)
void classifier_mfma(const bf16_t* __restrict__ h, const bf16_t* __restrict__ wcls,
                     const float* __restrict__ bcls, float* __restrict__ out)
{
    __shared__ __align__(16) bf16_t Ash[CBM][CLDK];
    __shared__ __align__(16) bf16_t Bsh[80][CLDK];

    const int tid = threadIdx.x;
    const int m0 = blockIdx.x * CBM;
    const int wave = tid >> 6, lane = tid & 63;
    const int wm = wave * 32;
    const int q = lane >> 4, l16 = lane & 15;

    floatx4 acc[2][5];
#pragma unroll
    for (int i = 0; i < 2; i++)
#pragma unroll
        for (int j = 0; j < 5; j++) acc[i][j] = (floatx4){0.f, 0.f, 0.f, 0.f};

    for (int kk = 0; kk < HID; kk += 64) {
#pragma unroll
        for (int it = 0; it < 4; it++) {
            int idx = tid + it * 256, r = idx >> 3, c = (idx & 7) * 8;
            *(uint4*)&Ash[r][c] = *(const uint4*)&h[(m0 + r) * HID + kk + c];
        }
#pragma unroll
        for (int it = 0; it < 3; it++) {
            int idx = tid + it * 256;
            if (idx < 640) {
                int r = idx >> 3, c = (idx & 7) * 8;
                *(uint4*)&Bsh[r][c] = *(const uint4*)&wcls[r * HID + kk + c];
            }
        }
        __syncthreads();
#pragma unroll
        for (int ks = 0; ks < 64; ks += 32) {
            bf16x8 af[2], bfr[5];
#pragma unroll
            for (int mi = 0; mi < 2; mi++)
                af[mi] = *(const bf16x8*)&Ash[wm + mi * 16 + l16][ks + q * 8];
#pragma unroll
            for (int ni = 0; ni < 5; ni++)
                bfr[ni] = *(const bf16x8*)&Bsh[ni * 16 + l16][ks + q * 8];
#pragma unroll
            for (int mi = 0; mi < 2; mi++)
#pragma unroll
                for (int ni = 0; ni < 5; ni++)
                    acc[mi][ni] = __builtin_amdgcn_mfma_f32_16x16x32_bf16(
                        af[mi], bfr[ni], acc[mi][ni], 0, 0, 0);
        }
        __syncthreads();
    }

#pragma unroll
    for (int mi = 0; mi < 2; mi++) {
#pragma unroll
        for (int r = 0; r < 4; r++) {
            int gm = m0 + wm + mi * 16 + q * 4 + r;
#pragma unroll
            for (int ni = 0; ni < 5; ni++) {
                int gn = ni * 16 + l16;
                if (gn < SEN + 1)
                    out[gm * (SEN + 1) + gn] = acc[mi][ni][r] + bcls[gn];
            }
        }
    }
}

extern "C" void kernel_launch(void* const* d_in, const int* in_sizes, int n_in,
                              void* d_out, int out_size, void* d_ws, size_t ws_size,
                              hipStream_t stream)
{
    const int*   x     = (const int*)  d_in[0];
    const float* emb   = (const float*)d_in[1];
    const float* w_ih  = (const float*)d_in[2];
    const float* w_hh  = (const float*)d_in[3];
    const float* w_cls = (const float*)d_in[4];
    const float* b_cls = (const float*)d_in[5];
    float* out = (float*)d_out;

    char* ws = (char*)d_ws;
    bf16_t* whh_bf  = (bf16_t*)ws;                                  // 2 MB
    float*  proj    = (float*)(ws + (2u << 20));                    // 128 KB
    bf16_t* wcls_bf = (bf16_t*)(ws + (2u << 20) + (128u << 10));    // 160 KB
    bf16_t* h0      = (bf16_t*)(ws + (2u << 20) + (288u << 10));    // 4 MB
    bf16_t* h1      = (bf16_t*)(ws + (6u << 20) + (288u << 10));    // 4 MB
    int*    scnt    = (int*)   (ws + (10u << 20) + (288u << 10));   // sync area

    hipMemsetAsync(scnt, 0, 16384, stream);
    cvt_whh<<<(HID * HID) / 256, 256, 0, stream>>>(w_hh, whh_bf, HID * HID);
    proj_kernel<<<(VOCAB * HID + 255) / 256, 256, 0, stream>>>(emb, w_ih, proj);
    cvt_wcls<<<(80 * HID) / 256, 256, 0, stream>>>(w_cls, wcls_bf);

    dim3 grid(BATCH / BM, HID / BN);   // (16,16) = 256 blocks = 1/CU (128 KB LDS)
    rnn_persist<<<grid, 512, 0, stream>>>(whh_bf, proj, x, h0, scnt);

    classifier_mfma<<<BATCH / CBM, 256, 0, stream>>>(h1, wcls_bf, b_cls, out);
}